// Round 6
// baseline (169.652 us; speedup 1.0000x reference)
//
#include <hip/hip_runtime.h>

// Problem constants
#define B_   64
#define M_   256
#define D_   256
#define A_   18
#define E_   4
#define S_   64
#define ES_  256          // E_*S_ == M_
#define H_   512
#define K2_  (A_*D_)      // 4608

typedef _Float16 f16;
typedef _Float16 f16x4 __attribute__((ext_vector_type(4)));
typedef _Float16 f16x8 __attribute__((ext_vector_type(8)));
typedef float    f32x4 __attribute__((ext_vector_type(4)));

// ===========================================================================
// fp32 src [z][R][C] -> fp16 dst [z][C][R]  (transpose + convert) — weights
// ===========================================================================
__global__ __launch_bounds__(256) void k_tcvt(
    const float* __restrict__ src, f16* __restrict__ dst,
    int R, int C, long sbs, long dbs)
{
  __shared__ f16 T[64][68];
  const int t = threadIdx.x;
  const int rr = t >> 4, cc = (t & 15) * 4;
  const int r0 = blockIdx.y * 64, c0 = blockIdx.x * 64;
  src += (long)blockIdx.z * sbs;
  dst += (long)blockIdx.z * dbs;
#pragma unroll
  for (int p = 0; p < 4; ++p) {
    const int row = rr + p * 16;
    const float4 v = *reinterpret_cast<const float4*>(
        &src[(long)(r0 + row) * C + c0 + cc]);
    T[row][cc + 0] = (f16)v.x; T[row][cc + 1] = (f16)v.y;
    T[row][cc + 2] = (f16)v.z; T[row][cc + 3] = (f16)v.w;
  }
  __syncthreads();
#pragma unroll
  for (int p = 0; p < 4; ++p) {
    const int oc = rr + p * 16;
    f16x4 g;
#pragma unroll
    for (int i = 0; i < 4; ++i) g[i] = T[cc + i][oc];
    *reinterpret_cast<f16x4*>(&dst[(long)(c0 + oc) * R + r0 + cc]) = g;
  }
}

// obs fp32 [b][M][D] -> obs16 [b][M][D] and obsT16 [b][D][M]
__global__ __launch_bounds__(256) void k_cvt_obs(
    const float* __restrict__ obs, f16* __restrict__ o16, f16* __restrict__ oT)
{
  __shared__ f16 T[64][68];
  const int t = threadIdx.x, rr = t >> 4, cc = (t & 15) * 4;
  const int r0 = blockIdx.y * 64, c0 = blockIdx.x * 64;
  const long bo = (long)blockIdx.z * (M_ * D_);
#pragma unroll
  for (int p = 0; p < 4; ++p) {
    const int row = rr + p * 16;
    const float4 v = *reinterpret_cast<const float4*>(
        &obs[bo + (long)(r0 + row) * D_ + c0 + cc]);
    f16x4 h; h[0] = (f16)v.x; h[1] = (f16)v.y; h[2] = (f16)v.z; h[3] = (f16)v.w;
    *reinterpret_cast<f16x4*>(&o16[bo + (long)(r0 + row) * D_ + c0 + cc]) = h;
    T[row][cc + 0] = h[0]; T[row][cc + 1] = h[1];
    T[row][cc + 2] = h[2]; T[row][cc + 3] = h[3];
  }
  __syncthreads();
#pragma unroll
  for (int p = 0; p < 4; ++p) {
    const int oc = rr + p * 16;
    f16x4 g;
#pragma unroll
    for (int i = 0; i < 4; ++i) g[i] = T[cc + i][oc];
    *reinterpret_cast<f16x4*>(&oT[bo + (long)(c0 + oc) * M_ + r0 + cc]) = g;
  }
}

// ===========================================================================
// MFMA GEMM core (f16 operands, K-contiguous both sides), 64x64 tile,
// 256 threads = 4 waves in 2x2; OUT_MODE: 0 f16 [M][N], 1 f16 [N][M], 2 f32.
// ===========================================================================
template<int RELU, int HAS_BIAS, int OUT_MODE>
__device__ __forceinline__ void mfma_gemm(
    const f16* __restrict__ A, int lda,
    const f16* __restrict__ BT, int ldb,
    const float* __restrict__ bias,
    void* __restrict__ Cout, int ldc, int K)
{
  const int t    = threadIdx.x;
  const int w    = t >> 6, lane = t & 63;
  const int wr   = w >> 1, wc = w & 1;
  const int m0   = blockIdx.y * 64 + wr * 32;
  const int n0   = blockIdx.x * 64 + wc * 32;
  const int lr   = lane & 15;
  const int lk   = (lane >> 4) * 8;

  f32x4 acc00 = {}, acc01 = {}, acc10 = {}, acc11 = {};
  const f16* Ap = A  + (long)(m0 + lr) * lda + lk;
  const f16* Bp = BT + (long)(n0 + lr) * ldb + lk;

  for (int k0 = 0; k0 < K; k0 += 32) {
    const f16x8 a0 = *reinterpret_cast<const f16x8*>(Ap);
    const f16x8 a1 = *reinterpret_cast<const f16x8*>(Ap + (long)16 * lda);
    const f16x8 b0 = *reinterpret_cast<const f16x8*>(Bp);
    const f16x8 b1 = *reinterpret_cast<const f16x8*>(Bp + (long)16 * ldb);
    acc00 = __builtin_amdgcn_mfma_f32_16x16x32_f16(a0, b0, acc00, 0, 0, 0);
    acc01 = __builtin_amdgcn_mfma_f32_16x16x32_f16(a0, b1, acc01, 0, 0, 0);
    acc10 = __builtin_amdgcn_mfma_f32_16x16x32_f16(a1, b0, acc10, 0, 0, 0);
    acc11 = __builtin_amdgcn_mfma_f32_16x16x32_f16(a1, b1, acc11, 0, 0, 0);
    Ap += 32; Bp += 32;
  }

  const int orow = (lane >> 4) * 4;
  f32x4 accs[2][2] = {{acc00, acc01}, {acc10, acc11}};
#pragma unroll
  for (int fi = 0; fi < 2; ++fi) {
#pragma unroll
    for (int fj = 0; fj < 2; ++fj) {
      const int gm = m0 + fi * 16 + orow;
      const int gn = n0 + fj * 16 + lr;
      f32x4 v = accs[fi][fj];
      if (HAS_BIAS) {
        const float bv = bias[gn];
        v[0] += bv; v[1] += bv; v[2] += bv; v[3] += bv;
      }
      if (RELU) {
#pragma unroll
        for (int r = 0; r < 4; ++r) v[r] = fmaxf(v[r], 0.f);
      }
      if (OUT_MODE == 0) {
        f16* C = (f16*)Cout;
#pragma unroll
        for (int r = 0; r < 4; ++r) C[(long)(gm + r) * ldc + gn] = (f16)v[r];
      } else if (OUT_MODE == 1) {
        f16x4 h4; h4[0] = (f16)v[0]; h4[1] = (f16)v[1];
        h4[2] = (f16)v[2]; h4[3] = (f16)v[3];
        *reinterpret_cast<f16x4*>(&((f16*)Cout)[(long)gn * ldc + gm]) = h4;
      } else {
        float* C = (float*)Cout;
#pragma unroll
        for (int r = 0; r < 4; ++r) C[(long)(gm + r) * ldc + gn] = v[r];
      }
    }
  }
}

// logits16[b][m][es] = obs16[b] @ phiT^T
__global__ __launch_bounds__(256) void k_logits(
    const f16* __restrict__ obs16, const f16* __restrict__ phiT,
    f16* __restrict__ logits16)
{
  const long b = blockIdx.z;
  mfma_gemm<0, 0, 0>(obs16 + b * (M_ * D_), D_, phiT, D_, nullptr,
                     logits16 + b * (M_ * ES_), ES_, D_);
}

// slots16[b][es][d] = dispT16[b] @ obsT16[b]^T   (K = m)
__global__ __launch_bounds__(256) void k_slots(
    const f16* __restrict__ dispT, const f16* __restrict__ obsT,
    f16* __restrict__ slots16)
{
  const long b = blockIdx.z;
  mfma_gemm<0, 0, 0>(dispT + b * (ES_ * M_), M_, obsT + b * (D_ * M_), M_,
                     nullptr, slots16 + b * (ES_ * D_), D_, M_);
}

// h16[z][s][h] = relu(slots16[b,e] @ w1T[e]^T + b1[e])
__global__ __launch_bounds__(256) void k_h(
    const f16* __restrict__ slots16, const f16* __restrict__ w1T,
    const float* __restrict__ b1, f16* __restrict__ h16)
{
  const long z = blockIdx.z; const long e = z & 3;
  mfma_gemm<1, 1, 0>(slots16 + z * (S_ * D_), D_,
                     w1T + e * (H_ * D_), D_,
                     b1 + e * H_,
                     h16 + z * (S_ * H_), H_, D_);
}

// yT16[b][d][es] = (h16[b,e] @ w2T[e, a-slice]^T + b2 slice), transposed write
__global__ __launch_bounds__(256) void k_y(
    const f16* __restrict__ h16, const f16* __restrict__ w2T,
    const float* __restrict__ b2, const int* __restrict__ action,
    f16* __restrict__ yT16)
{
  const long z = blockIdx.z; const long b = z >> 2, e = z & 3;
  int a = action[b];
  a = (a < 0) ? 0 : (a >= A_ ? A_ - 1 : a);
  mfma_gemm<0, 1, 1>(h16 + z * (S_ * H_), H_,
                     w2T + e * ((long)K2_ * H_) + (long)a * D_ * H_, H_,
                     b2 + e * K2_ + a * D_,
                     yT16 + b * (D_ * ES_) + e * S_, ES_, H_);
}

// out[b][m][d] (fp32) = comb16[b] @ yT16[b]^T   (K = es)
__global__ __launch_bounds__(256) void k_out(
    const f16* __restrict__ comb16, const f16* __restrict__ yT16,
    float* __restrict__ out)
{
  const long b = blockIdx.z;
  mfma_gemm<0, 0, 2>(comb16 + b * (M_ * ES_), ES_, yT16 + b * (D_ * ES_), ES_,
                     nullptr, out + b * (M_ * D_), D_, ES_);
}

// ===========================================================================
// dispatch softmax over tokens m + transposed write: dispT[b][es][m]
// grid (ES_/64, B_), 256 threads
// ===========================================================================
__global__ __launch_bounds__(256) void k_dispatchT(
    const f16* __restrict__ logits16, f16* __restrict__ dispT16)
{
  const int t = threadIdx.x;
  const int x = t & 63, g = t >> 6;
  const int es0 = blockIdx.x * 64;
  const long bbase = (long)blockIdx.y * (M_ * ES_);

  // phase 1: column stats (max, sum) for es0 + x
  float mx = -1e30f, sm = 0.f;
  for (int m = g; m < M_; m += 4) {
    const float v  = (float)logits16[bbase + (long)m * ES_ + es0 + x];
    const float nm = fmaxf(mx, v);
    sm = sm * __expf(mx - nm) + __expf(v - nm);
    mx = nm;
  }
  __shared__ float smx[4][64], ssm[4][64];
  __shared__ float cmax[64], cinv[64];
  smx[g][x] = mx; ssm[g][x] = sm;
  __syncthreads();
  if (t < 64) {
    float M0 = smx[0][t], S0 = ssm[0][t];
#pragma unroll
    for (int i = 1; i < 4; ++i) {
      const float Mi = smx[i][t], Si = ssm[i][t];
      const float nm = fmaxf(M0, Mi);
      S0 = S0 * __expf(M0 - nm) + Si * __expf(Mi - nm);
      M0 = nm;
    }
    cmax[t] = M0; cinv[t] = 1.0f / S0;
  }
  __syncthreads();

  // phase 2: tile-wise exp + transpose through LDS, coalesced write
  __shared__ f16 T[64][68];
  const int rr = t >> 4, cc4 = (t & 15) * 4;
  for (int m0 = 0; m0 < M_; m0 += 64) {
#pragma unroll
    for (int p = 0; p < 4; ++p) {
      const int mr = rr + p * 16;
      const f16x4 v = *reinterpret_cast<const f16x4*>(
          &logits16[bbase + (long)(m0 + mr) * ES_ + es0 + cc4]);
#pragma unroll
      for (int i = 0; i < 4; ++i) {
        const int es = cc4 + i;
        T[es][mr] = (f16)(__expf((float)v[i] - cmax[es]) * cinv[es]);
      }
    }
    __syncthreads();
#pragma unroll
    for (int p = 0; p < 4; ++p) {
      const int er = rr + p * 16;
      const f16x4 gv = *reinterpret_cast<const f16x4*>(&T[er][cc4]);
      *reinterpret_cast<f16x4*>(
          &dispT16[bbase + (long)(es0 + er) * M_ + m0 + cc4]) = gv;
    }
    __syncthreads();
  }
}

// combine: softmax over all ES slots per (b,m) row
__global__ __launch_bounds__(256) void k_combine(
    const f16* __restrict__ logits16, f16* __restrict__ comb16)
{
  const int t = threadIdx.x;
  const int lane = t & 63, wv = t >> 6;
  const long row = (long)blockIdx.x * 4 + wv;
  const f16x4 v = *reinterpret_cast<const f16x4*>(&logits16[row * ES_ + lane * 4]);
  float f0 = (float)v[0], f1 = (float)v[1], f2 = (float)v[2], f3 = (float)v[3];
  float mx = fmaxf(fmaxf(f0, f1), fmaxf(f2, f3));
#pragma unroll
  for (int o = 32; o; o >>= 1) mx = fmaxf(mx, __shfl_xor(mx, o));
  const float e0 = __expf(f0 - mx), e1 = __expf(f1 - mx);
  const float e2 = __expf(f2 - mx), e3 = __expf(f3 - mx);
  float sm = e0 + e1 + e2 + e3;
#pragma unroll
  for (int o = 32; o; o >>= 1) sm += __shfl_xor(sm, o);
  const float inv = 1.0f / sm;
  f16x4 r; r[0] = (f16)(e0 * inv); r[1] = (f16)(e1 * inv);
  r[2] = (f16)(e2 * inv); r[3] = (f16)(e3 * inv);
  *reinterpret_cast<f16x4*>(&comb16[row * ES_ + lane * 4]) = r;
}

// ===========================================================================
extern "C" void kernel_launch(void* const* d_in, const int* in_sizes, int n_in,
                              void* d_out, int out_size, void* d_ws, size_t ws_size,
                              hipStream_t stream)
{
  const float* obs    = (const float*)d_in[0];
  const int*   action = (const int*)d_in[1];
  const float* phi    = (const float*)d_in[2];
  const float* w1     = (const float*)d_in[3];
  const float* b1     = (const float*)d_in[4];
  const float* w2     = (const float*)d_in[5];
  const float* b2     = (const float*)d_in[6];
  float*       out    = (float*)d_out;

  // Workspace layout (f16 units), 78.8 MB total — identical to R4.
  f16* ws = (f16*)d_ws;
  f16* obs16    = ws + 0;          // dead after k_logits
  f16* obsT16   = ws + 4194304;    // dead after k_slots
  f16* phiT     = ws + 8388608;
  f16* w1T      = ws + 8454144;
  f16* w2T      = ws + 8978432;
  f16* logits16 = ws + 18415616;
  f16* dispT16  = ws + 22609920;
  f16* comb16   = ws + 26804224;
  f16* slots16  = ws + 30998528;
  f16* yT16     = ws + 35192832;
  f16* h16      = ws + 0;          // alias: spans obs16+obsT16 (both dead)

  // --- one-time conversions ---
  k_cvt_obs<<<dim3(4, 4, 64), 256, 0, stream>>>(obs, obs16, obsT16);
  k_tcvt   <<<dim3(4, 4, 1),  256, 0, stream>>>(phi, phiT, 256, 256, 0, 0);
  k_tcvt   <<<dim3(8, 4, 4),  256, 0, stream>>>(w1, w1T, D_, H_,
                                                (long)D_ * H_, (long)H_ * D_);
  k_tcvt   <<<dim3(72, 8, 4), 256, 0, stream>>>(w2, w2T, H_, K2_,
                                                (long)H_ * K2_, (long)K2_ * H_);
  // --- pipeline ---
  k_logits   <<<dim3(4, 4, 64), 256, 0, stream>>>(obs16, phiT, logits16);
  k_dispatchT<<<dim3(4, 64),    256, 0, stream>>>(logits16, dispT16);
  k_combine  <<<dim3(4096),     256, 0, stream>>>(logits16, comb16);
  k_slots    <<<dim3(4, 4, 64), 256, 0, stream>>>(dispT16, obsT16, slots16);
  k_h        <<<dim3(8, 1, 256),256, 0, stream>>>(slots16, w1T, b1, h16);
  k_y        <<<dim3(4, 1, 256),256, 0, stream>>>(h16, w2T, b2, action, yT16);
  k_out      <<<dim3(4, 4, 64), 256, 0, stream>>>(comb16, yT16, out);
}

// Round 7
// 138.450 us; speedup vs baseline: 1.2254x; 1.2254x over previous
//
#include <hip/hip_runtime.h>

// Problem constants
#define B_   64
#define M_   256
#define D_   256
#define A_   18
#define E_   4
#define S_   64
#define ES_  256          // E_*S_ == M_
#define H_   512
#define K2_  (A_*D_)      // 4608

typedef _Float16 f16;
typedef _Float16 f16x4 __attribute__((ext_vector_type(4)));
typedef _Float16 f16x8 __attribute__((ext_vector_type(8)));
typedef float    f32x4 __attribute__((ext_vector_type(4)));

// ===========================================================================
// Conversion / transpose kernels (one-time per call)
// ===========================================================================

// fp32 src [z][R][C] -> fp16 dst [z][C][R]  (transpose + convert)
__global__ __launch_bounds__(256) void k_tcvt(
    const float* __restrict__ src, f16* __restrict__ dst,
    int R, int C, long sbs, long dbs)
{
  __shared__ f16 T[64][68];
  const int t = threadIdx.x;
  const int rr = t >> 4, cc = (t & 15) * 4;
  const int r0 = blockIdx.y * 64, c0 = blockIdx.x * 64;
  src += (long)blockIdx.z * sbs;
  dst += (long)blockIdx.z * dbs;
#pragma unroll
  for (int p = 0; p < 4; ++p) {
    const int row = rr + p * 16;
    const float4 v = *reinterpret_cast<const float4*>(
        &src[(long)(r0 + row) * C + c0 + cc]);
    T[row][cc + 0] = (f16)v.x; T[row][cc + 1] = (f16)v.y;
    T[row][cc + 2] = (f16)v.z; T[row][cc + 3] = (f16)v.w;
  }
  __syncthreads();
#pragma unroll
  for (int p = 0; p < 4; ++p) {
    const int oc = rr + p * 16;          // src-col index = dst row
    f16x4 g;
#pragma unroll
    for (int i = 0; i < 4; ++i) g[i] = T[cc + i][oc];
    *reinterpret_cast<f16x4*>(&dst[(long)(c0 + oc) * R + r0 + cc]) = g;
  }
}

// obs fp32 [b][M][D] -> obs16 [b][M][D] and obsT16 [b][D][M]
__global__ __launch_bounds__(256) void k_cvt_obs(
    const float* __restrict__ obs, f16* __restrict__ o16, f16* __restrict__ oT)
{
  __shared__ f16 T[64][68];
  const int t = threadIdx.x, rr = t >> 4, cc = (t & 15) * 4;
  const int r0 = blockIdx.y * 64, c0 = blockIdx.x * 64;
  const long bo = (long)blockIdx.z * (M_ * D_);
#pragma unroll
  for (int p = 0; p < 4; ++p) {
    const int row = rr + p * 16;
    const float4 v = *reinterpret_cast<const float4*>(
        &obs[bo + (long)(r0 + row) * D_ + c0 + cc]);
    f16x4 h; h[0] = (f16)v.x; h[1] = (f16)v.y; h[2] = (f16)v.z; h[3] = (f16)v.w;
    *reinterpret_cast<f16x4*>(&o16[bo + (long)(r0 + row) * D_ + c0 + cc]) = h;
    T[row][cc + 0] = h[0]; T[row][cc + 1] = h[1];
    T[row][cc + 2] = h[2]; T[row][cc + 3] = h[3];
  }
  __syncthreads();
#pragma unroll
  for (int p = 0; p < 4; ++p) {
    const int oc = rr + p * 16;
    f16x4 g;
#pragma unroll
    for (int i = 0; i < 4; ++i) g[i] = T[cc + i][oc];
    *reinterpret_cast<f16x4*>(&oT[bo + (long)(c0 + oc) * M_ + r0 + cc]) = g;
  }
}

// ===========================================================================
// MFMA GEMM core: C[64x64 tile] = A[M][K] * BT[N][K]^T
// 256 threads = 4 waves; wave (wr,wc) owns a 32x32 quadrant (2x2 frags).
// OUT_MODE: 0 = fp16 normal [M][N], 2 = fp32 [M][N]
// ===========================================================================
template<int OUT_MODE>
__device__ __forceinline__ void mfma_gemm(
    const f16* __restrict__ A, int lda,
    const f16* __restrict__ BT, int ldb,
    void* __restrict__ Cout, int ldc, int K)
{
  const int t    = threadIdx.x;
  const int w    = t >> 6, lane = t & 63;
  const int wr   = w >> 1, wc = w & 1;
  const int m0   = blockIdx.y * 64 + wr * 32;
  const int n0   = blockIdx.x * 64 + wc * 32;
  const int lr   = lane & 15;
  const int lk   = (lane >> 4) * 8;       // k-offset within 32-wide step

  f32x4 acc00 = {}, acc01 = {}, acc10 = {}, acc11 = {};
  const f16* Ap = A  + (long)(m0 + lr) * lda + lk;
  const f16* Bp = BT + (long)(n0 + lr) * ldb + lk;

  for (int k0 = 0; k0 < K; k0 += 32) {
    const f16x8 a0 = *reinterpret_cast<const f16x8*>(Ap);
    const f16x8 a1 = *reinterpret_cast<const f16x8*>(Ap + (long)16 * lda);
    const f16x8 b0 = *reinterpret_cast<const f16x8*>(Bp);
    const f16x8 b1 = *reinterpret_cast<const f16x8*>(Bp + (long)16 * ldb);
    acc00 = __builtin_amdgcn_mfma_f32_16x16x32_f16(a0, b0, acc00, 0, 0, 0);
    acc01 = __builtin_amdgcn_mfma_f32_16x16x32_f16(a0, b1, acc01, 0, 0, 0);
    acc10 = __builtin_amdgcn_mfma_f32_16x16x32_f16(a1, b0, acc10, 0, 0, 0);
    acc11 = __builtin_amdgcn_mfma_f32_16x16x32_f16(a1, b1, acc11, 0, 0, 0);
    Ap += 32; Bp += 32;
  }

  const int orow = (lane >> 4) * 4;
  f32x4 accs[2][2] = {{acc00, acc01}, {acc10, acc11}};
#pragma unroll
  for (int fi = 0; fi < 2; ++fi) {
#pragma unroll
    for (int fj = 0; fj < 2; ++fj) {
      const int gm = m0 + fi * 16 + orow;
      const int gn = n0 + fj * 16 + lr;
      f32x4 v = accs[fi][fj];
      if (OUT_MODE == 0) {
        f16* C = (f16*)Cout;
#pragma unroll
        for (int r = 0; r < 4; ++r) C[(long)(gm + r) * ldc + gn] = (f16)v[r];
      } else {
        float* C = (float*)Cout;
#pragma unroll
        for (int r = 0; r < 4; ++r) C[(long)(gm + r) * ldc + gn] = v[r];
      }
    }
  }
}

// logits16[b][m][es] = obs16[b] @ phiT^T
__global__ __launch_bounds__(256) void k_logits(
    const f16* __restrict__ obs16, const f16* __restrict__ phiT,
    f16* __restrict__ logits16)
{
  const long b = blockIdx.z;
  mfma_gemm<0>(obs16 + b * (M_ * D_), D_, phiT, D_,
               logits16 + b * (M_ * ES_), ES_, D_);
}

// slots16[b][es][d] = dispT16[b] @ obsT16[b]^T   (K = m)
__global__ __launch_bounds__(256) void k_slots(
    const f16* __restrict__ dispT, const f16* __restrict__ obsT,
    f16* __restrict__ slots16)
{
  const long b = blockIdx.z;
  mfma_gemm<0>(dispT + b * (ES_ * M_), M_, obsT + b * (D_ * M_), M_,
               slots16 + b * (ES_ * D_), D_, M_);
}

// out[b][m][d] (fp32) = comb16[b] @ yT16[b]^T   (K = es)
__global__ __launch_bounds__(256) void k_out(
    const f16* __restrict__ comb16, const f16* __restrict__ yT16,
    float* __restrict__ out)
{
  const long b = blockIdx.z;
  mfma_gemm<2>(comb16 + b * (M_ * ES_), ES_, yT16 + b * (D_ * ES_), ES_,
               out + b * (M_ * D_), D_, ES_);
}

// ===========================================================================
// dispatch softmax over tokens m + transposed write: dispT[b][es][m]
// grid (ES_/64, B_), 256 threads
// ===========================================================================
__global__ __launch_bounds__(256) void k_dispatchT(
    const f16* __restrict__ logits16, f16* __restrict__ dispT16)
{
  const int t = threadIdx.x;
  const int x = t & 63, g = t >> 6;
  const int es0 = blockIdx.x * 64;
  const long bbase = (long)blockIdx.y * (M_ * ES_);

  // phase 1: column stats (max, sum) for es0 + x
  float mx = -1e30f, sm = 0.f;
  for (int m = g; m < M_; m += 4) {
    const float v  = (float)logits16[bbase + (long)m * ES_ + es0 + x];
    const float nm = fmaxf(mx, v);
    sm = sm * __expf(mx - nm) + __expf(v - nm);
    mx = nm;
  }
  __shared__ float smx[4][64], ssm[4][64];
  __shared__ float cmax[64], cinv[64];
  smx[g][x] = mx; ssm[g][x] = sm;
  __syncthreads();
  if (t < 64) {
    float M0 = smx[0][t], S0 = ssm[0][t];
#pragma unroll
    for (int i = 1; i < 4; ++i) {
      const float Mi = smx[i][t], Si = ssm[i][t];
      const float nm = fmaxf(M0, Mi);
      S0 = S0 * __expf(M0 - nm) + Si * __expf(Mi - nm);
      M0 = nm;
    }
    cmax[t] = M0; cinv[t] = 1.0f / S0;
  }
  __syncthreads();

  // phase 2: tile-wise exp + transpose through LDS, coalesced write
  __shared__ f16 T[64][68];
  const int rr = t >> 4, cc4 = (t & 15) * 4;
  for (int m0 = 0; m0 < M_; m0 += 64) {
#pragma unroll
    for (int p = 0; p < 4; ++p) {
      const int mr = rr + p * 16;
      const f16x4 v = *reinterpret_cast<const f16x4*>(
          &logits16[bbase + (long)(m0 + mr) * ES_ + es0 + cc4]);
#pragma unroll
      for (int i = 0; i < 4; ++i) {
        const int es = cc4 + i;
        T[es][mr] = (f16)(__expf((float)v[i] - cmax[es]) * cinv[es]);
      }
    }
    __syncthreads();
#pragma unroll
    for (int p = 0; p < 4; ++p) {
      const int er = rr + p * 16;
      const f16x4 gv = *reinterpret_cast<const f16x4*>(&T[er][cc4]);
      *reinterpret_cast<f16x4*>(
          &dispT16[bbase + (long)(es0 + er) * M_ + m0 + cc4]) = gv;
    }
    __syncthreads();
  }
}

// combine: softmax over all ES slots per (b,m) row
__global__ __launch_bounds__(256) void k_combine(
    const f16* __restrict__ logits16, f16* __restrict__ comb16)
{
  const int t = threadIdx.x;
  const int lane = t & 63, wv = t >> 6;
  const long row = (long)blockIdx.x * 4 + wv;
  const f16x4 v = *reinterpret_cast<const f16x4*>(&logits16[row * ES_ + lane * 4]);
  float f0 = (float)v[0], f1 = (float)v[1], f2 = (float)v[2], f3 = (float)v[3];
  float mx = fmaxf(fmaxf(f0, f1), fmaxf(f2, f3));
#pragma unroll
  for (int o = 32; o; o >>= 1) mx = fmaxf(mx, __shfl_xor(mx, o));
  const float e0 = __expf(f0 - mx), e1 = __expf(f1 - mx);
  const float e2 = __expf(f2 - mx), e3 = __expf(f3 - mx);
  float sm = e0 + e1 + e2 + e3;
#pragma unroll
  for (int o = 32; o; o >>= 1) sm += __shfl_xor(sm, o);
  const float inv = 1.0f / sm;
  f16x4 r; r[0] = (f16)(e0 * inv); r[1] = (f16)(e1 * inv);
  r[2] = (f16)(e2 * inv); r[3] = (f16)(e3 * inv);
  *reinterpret_cast<f16x4*>(&comb16[row * ES_ + lane * 4]) = r;
}

// ===========================================================================
// Fused h->y kernel per (b,e): h = relu(slots @ w1T^T + b1) kept in LDS,
// then yT16[b][d][es] = (h @ w2T[a-slice]^T + b2 slice) transposed write.
// 512 threads = 8 waves, 1 block/CU (66.5 KB LDS) -> 2 waves/SIMD.
// __launch_bounds__(512, 2): tell the allocator 2 waves/SIMD is the target,
// unlocking the full VGPR budget for register double-buffer prefetch that
// hides the ~500-cyc L2 latency under the MFMA stream.
// ===========================================================================
#define HPAD 520   // 512 + 8 f16 pad

__global__ __launch_bounds__(512, 2) void k_hy(
    const f16* __restrict__ slots16, const f16* __restrict__ w1T,
    const float* __restrict__ b1, const f16* __restrict__ w2T,
    const float* __restrict__ b2, const int* __restrict__ action,
    f16* __restrict__ yT16)
{
  __shared__ f16 hs[64][HPAD];
  const int z = blockIdx.x;
  const int b = z >> 2, e = z & 3;
  int a = action[b];
  a = (a < 0) ? 0 : (a >= A_ ? A_ - 1 : a);

  const int t = threadIdx.x, w = t >> 6, lane = t & 63;
  const int lr = lane & 15, lk = (lane >> 4) * 8;
  const int orow = (lane >> 4) * 4;

  // GEMM2 B pointer (wave grid 2x4) — first fragments prefetched during GEMM1
  const int wr2 = w >> 2, wc2 = w & 3;
  const int m0_2 = wr2 * 32, n0_2 = wc2 * 64;
  const f16* Bp2 = w2T + (long)e * ((long)K2_ * H_)
                 + ((long)a * D_ + n0_2 + lr) * H_ + lk;

  // ---- GEMM1: h[64][512] = relu(slots[64x256] @ w1T[e][512x256]^T + b1) ---
  {
    const int n0 = w * 64;                 // wave covers h-cols n0..n0+63
    f32x4 acc[4][4] = {};
    const f16* Ap = slots16 + (long)z * (S_ * D_) + (long)lr * D_ + lk;
    const f16* Bp = w1T + (long)e * (H_ * D_) + (long)(n0 + lr) * D_ + lk;

    f16x8 afc[4], bfc[4], afn[4], bfn[4];
#pragma unroll
    for (int fi = 0; fi < 4; ++fi)
      afc[fi] = *reinterpret_cast<const f16x8*>(Ap + (long)fi * 16 * D_);
#pragma unroll
    for (int fj = 0; fj < 4; ++fj)
      bfc[fj] = *reinterpret_cast<const f16x8*>(Bp + (long)fj * 16 * D_);

#pragma unroll
    for (int it = 0; it < 8; ++it) {
      const int k1 = (it + 1) * 32;
      if (it < 7) {
#pragma unroll
        for (int fi = 0; fi < 4; ++fi)
          afn[fi] = *reinterpret_cast<const f16x8*>(Ap + (long)fi * 16 * D_ + k1);
#pragma unroll
        for (int fj = 0; fj < 4; ++fj)
          bfn[fj] = *reinterpret_cast<const f16x8*>(Bp + (long)fj * 16 * D_ + k1);
      }
#pragma unroll
      for (int fi = 0; fi < 4; ++fi)
#pragma unroll
        for (int fj = 0; fj < 4; ++fj)
          acc[fi][fj] = __builtin_amdgcn_mfma_f32_16x16x32_f16(
              afc[fi], bfc[fj], acc[fi][fj], 0, 0, 0);
#pragma unroll
      for (int q = 0; q < 4; ++q) { afc[q] = afn[q]; bfc[q] = bfn[q]; }
    }
#pragma unroll
    for (int fi = 0; fi < 4; ++fi)
#pragma unroll
      for (int fj = 0; fj < 4; ++fj) {
        const int gm = fi * 16 + orow;
        const int gn = n0 + fj * 16 + lr;
        const float bv = b1[e * H_ + gn];
#pragma unroll
        for (int r = 0; r < 4; ++r)
          hs[gm + r][gn] = (f16)fmaxf(acc[fi][fj][r] + bv, 0.f);
      }
  }

  // Prefetch GEMM2's first B fragments (global, independent of LDS) so the
  // load latency hides under the barrier drain.
  f16x8 bfc2[4], bfn2[4];
#pragma unroll
  for (int fj = 0; fj < 4; ++fj)
    bfc2[fj] = *reinterpret_cast<const f16x8*>(Bp2 + (long)fj * 16 * H_);

  __syncthreads();

  // ---- GEMM2: y[64 s][256 d] = h @ w2T[e][a*D..][512]^T + b2 slice --------
  {
    f32x4 acc[2][4] = {};
#pragma unroll
    for (int it = 0; it < 16; ++it) {
      const int k0 = it * 32;
      f16x8 af[2];
#pragma unroll
      for (int fi = 0; fi < 2; ++fi)
        af[fi] = *reinterpret_cast<const f16x8*>(&hs[m0_2 + fi * 16 + lr][k0 + lk]);
      if (it < 15) {
#pragma unroll
        for (int fj = 0; fj < 4; ++fj)
          bfn2[fj] = *reinterpret_cast<const f16x8*>(
              Bp2 + (long)fj * 16 * H_ + k0 + 32);
      }
#pragma unroll
      for (int fi = 0; fi < 2; ++fi)
#pragma unroll
        for (int fj = 0; fj < 4; ++fj)
          acc[fi][fj] = __builtin_amdgcn_mfma_f32_16x16x32_f16(
              af[fi], bfc2[fj], acc[fi][fj], 0, 0, 0);
#pragma unroll
      for (int q = 0; q < 4; ++q) bfc2[q] = bfn2[q];
    }
    // transposed write: yT16[b][d = gn][es = e*64 + gm .. +3]
#pragma unroll
    for (int fi = 0; fi < 2; ++fi)
#pragma unroll
      for (int fj = 0; fj < 4; ++fj) {
        const int gm = m0_2 + fi * 16 + orow;    // s
        const int gn = n0_2 + fj * 16 + lr;      // d
        const float bv = b2[e * K2_ + a * D_ + gn];
        f16x4 h4;
#pragma unroll
        for (int r = 0; r < 4; ++r) h4[r] = (f16)(acc[fi][fj][r] + bv);
        *reinterpret_cast<f16x4*>(
            &yT16[(long)b * (D_ * ES_) + (long)gn * ES_ + e * S_ + gm]) = h4;
      }
  }
}

// ===========================================================================
extern "C" void kernel_launch(void* const* d_in, const int* in_sizes, int n_in,
                              void* d_out, int out_size, void* d_ws, size_t ws_size,
                              hipStream_t stream)
{
  const float* obs    = (const float*)d_in[0];
  const int*   action = (const int*)d_in[1];
  const float* phi    = (const float*)d_in[2];
  const float* w1     = (const float*)d_in[3];
  const float* b1     = (const float*)d_in[4];
  const float* w2     = (const float*)d_in[5];
  const float* b2     = (const float*)d_in[6];
  float*       out    = (float*)d_out;

  // Workspace layout (f16 units, no aliasing, ~79 MB total) — identical to R4
  f16* ws = (f16*)d_ws;
  f16* obs16    = ws + 0;
  f16* obsT16   = ws + 4194304;
  f16* phiT     = ws + 8388608;
  f16* w1T      = ws + 8454144;
  f16* w2T      = ws + 8978432;
  f16* logits16 = ws + 18415616;
  f16* dispT16  = ws + 22609920;
  f16* comb16   = ws + 26804224;
  f16* slots16  = ws + 30998528;
  f16* yT16     = ws + 35192832;

  // --- one-time conversions ---
  k_cvt_obs<<<dim3(4, 4, 64), 256, 0, stream>>>(obs, obs16, obsT16);
  k_tcvt   <<<dim3(4, 4, 1),  256, 0, stream>>>(phi, phiT, 256, 256, 0, 0);
  k_tcvt   <<<dim3(8, 4, 4),  256, 0, stream>>>(w1, w1T, D_, H_,
                                                (long)D_ * H_, (long)H_ * D_);
  k_tcvt   <<<dim3(72, 8, 4), 256, 0, stream>>>(w2, w2T, H_, K2_,
                                                (long)H_ * K2_, (long)K2_ * H_);
  // --- pipeline ---
  k_logits   <<<dim3(4, 4, 64), 256, 0, stream>>>(obs16, phiT, logits16);
  k_dispatchT<<<dim3(4, 64),    256, 0, stream>>>(logits16, dispT16);
  k_combine  <<<dim3(4096),     256, 0, stream>>>(logits16, comb16);
  k_slots    <<<dim3(4, 4, 64), 256, 0, stream>>>(dispT16, obsT16, slots16);
  k_hy       <<<dim3(256),      512, 0, stream>>>(slots16, w1T, b1, w2T, b2,
                                                  action, yT16);
  k_out      <<<dim3(4, 4, 64), 256, 0, stream>>>(comb16, yT16, out);
}

// Round 8
// 121.498 us; speedup vs baseline: 1.3963x; 1.1395x over previous
//
#include <hip/hip_runtime.h>

// Problem constants
#define B_   64
#define M_   256
#define D_   256
#define A_   18
#define E_   4
#define S_   64
#define ES_  256          // E_*S_ == M_
#define H_   512
#define K2_  (A_*D_)      // 4608

typedef _Float16 f16;
typedef _Float16 f16x4 __attribute__((ext_vector_type(4)));
typedef _Float16 f16x8 __attribute__((ext_vector_type(8)));
typedef float    f32x4 __attribute__((ext_vector_type(4)));

static __device__ __forceinline__ f16x8 cat8(f16x4 a, f16x4 b) {
  return __builtin_shufflevector(a, b, 0, 1, 2, 3, 4, 5, 6, 7);
}

// ===========================================================================
// fp32 src [z][R][C] -> fp16 dst [z][C][R]  (transpose + convert) — weights
// ===========================================================================
__global__ __launch_bounds__(256) void k_tcvt(
    const float* __restrict__ src, f16* __restrict__ dst,
    int R, int C, long sbs, long dbs)
{
  __shared__ f16 T[64][68];
  const int t = threadIdx.x;
  const int rr = t >> 4, cc = (t & 15) * 4;
  const int r0 = blockIdx.y * 64, c0 = blockIdx.x * 64;
  src += (long)blockIdx.z * sbs;
  dst += (long)blockIdx.z * dbs;
#pragma unroll
  for (int p = 0; p < 4; ++p) {
    const int row = rr + p * 16;
    const float4 v = *reinterpret_cast<const float4*>(
        &src[(long)(r0 + row) * C + c0 + cc]);
    T[row][cc + 0] = (f16)v.x; T[row][cc + 1] = (f16)v.y;
    T[row][cc + 2] = (f16)v.z; T[row][cc + 3] = (f16)v.w;
  }
  __syncthreads();
#pragma unroll
  for (int p = 0; p < 4; ++p) {
    const int oc = rr + p * 16;
    f16x4 g;
#pragma unroll
    for (int i = 0; i < 4; ++i) g[i] = T[cc + i][oc];
    *reinterpret_cast<f16x4*>(&dst[(long)(c0 + oc) * R + r0 + cc]) = g;
  }
}

// obs fp32 [b][M][D] -> obs16 [b][M][D] and obsT16 [b][D][M]
__global__ __launch_bounds__(256) void k_cvt_obs(
    const float* __restrict__ obs, f16* __restrict__ o16, f16* __restrict__ oT)
{
  __shared__ f16 T[64][68];
  const int t = threadIdx.x, rr = t >> 4, cc = (t & 15) * 4;
  const int r0 = blockIdx.y * 64, c0 = blockIdx.x * 64;
  const long bo = (long)blockIdx.z * (M_ * D_);
#pragma unroll
  for (int p = 0; p < 4; ++p) {
    const int row = rr + p * 16;
    const float4 v = *reinterpret_cast<const float4*>(
        &obs[bo + (long)(r0 + row) * D_ + c0 + cc]);
    f16x4 h; h[0] = (f16)v.x; h[1] = (f16)v.y; h[2] = (f16)v.z; h[3] = (f16)v.w;
    *reinterpret_cast<f16x4*>(&o16[bo + (long)(r0 + row) * D_ + c0 + cc]) = h;
    T[row][cc + 0] = h[0]; T[row][cc + 1] = h[1];
    T[row][cc + 2] = h[2]; T[row][cc + 3] = h[3];
  }
  __syncthreads();
#pragma unroll
  for (int p = 0; p < 4; ++p) {
    const int oc = rr + p * 16;
    f16x4 g;
#pragma unroll
    for (int i = 0; i < 4; ++i) g[i] = T[cc + i][oc];
    *reinterpret_cast<f16x4*>(&oT[bo + (long)(c0 + oc) * M_ + r0 + cc]) = g;
  }
}

// ===========================================================================
// k_logits_f: per 64x64 tile of logits[b] = obs16[b] @ phiT^T:
//   exp16 [b][m][es]  = exp(logit)           (f16, no max-subtraction)
//   expT16[b][es][m]  = exp(logit) transposed
//   rowpart[b][m][esb]  = partial sum over this es-slice   (f32)
//   colpart[b][es][mb]  = partial sum over this m-slice    (f32)
// Softmax normalization is applied later in consumer epilogues.
// grid (4 es, 4 m, 64 b), 256 threads
// ===========================================================================
__global__ __launch_bounds__(256) void k_logits_f(
    const f16* __restrict__ obs16, const f16* __restrict__ phiT,
    f16* __restrict__ exp16, f16* __restrict__ expT16,
    float* __restrict__ rowpart, float* __restrict__ colpart)
{
  __shared__ f16 T[64][68];     // [m_local][es_local], stride 68 (8B-aligned x4)
  const int t = threadIdx.x;
  const int es0 = blockIdx.x * 64, m0g = blockIdx.y * 64;
  const int bz = blockIdx.z;
  const long bo = (long)bz * (M_ * D_);
  const long bb = (long)bz * (M_ * ES_);

  const int w = t >> 6, lane = t & 63;
  const int wr = w >> 1, wc = w & 1;
  const int lr = lane & 15, lk = (lane >> 4) * 8;
  const int orow = (lane >> 4) * 4;

  // ---- MFMA tile ----
  f32x4 acc[2][2] = {};
  const f16* Ap = obs16 + bo + (long)(m0g + wr * 32 + lr) * D_ + lk;
  const f16* Bp = phiT + (long)(es0 + wc * 32 + lr) * D_ + lk;
#pragma unroll
  for (int k0 = 0; k0 < D_; k0 += 32) {
    const f16x8 a0 = *reinterpret_cast<const f16x8*>(Ap + k0);
    const f16x8 a1 = *reinterpret_cast<const f16x8*>(Ap + 16 * D_ + k0);
    const f16x8 b0 = *reinterpret_cast<const f16x8*>(Bp + k0);
    const f16x8 b1 = *reinterpret_cast<const f16x8*>(Bp + 16 * D_ + k0);
    acc[0][0] = __builtin_amdgcn_mfma_f32_16x16x32_f16(a0, b0, acc[0][0], 0, 0, 0);
    acc[0][1] = __builtin_amdgcn_mfma_f32_16x16x32_f16(a0, b1, acc[0][1], 0, 0, 0);
    acc[1][0] = __builtin_amdgcn_mfma_f32_16x16x32_f16(a1, b0, acc[1][0], 0, 0, 0);
    acc[1][1] = __builtin_amdgcn_mfma_f32_16x16x32_f16(a1, b1, acc[1][1], 0, 0, 0);
  }
  // ---- exp -> LDS tile ----
#pragma unroll
  for (int fi = 0; fi < 2; ++fi)
#pragma unroll
    for (int fj = 0; fj < 2; ++fj) {
      const int gm = wr * 32 + fi * 16 + orow;
      const int gn = wc * 32 + fj * 16 + lr;
#pragma unroll
      for (int r = 0; r < 4; ++r)
        T[gm + r][gn] = (f16)__expf(acc[fi][fj][r]);
    }
  __syncthreads();

  // ---- phase 2a: write exp16 [m][es] rows ----
  {
    const int row = t >> 2, q = t & 3;
    f16x4 p0 = *reinterpret_cast<const f16x4*>(&T[row][q * 16 + 0]);
    f16x4 p1 = *reinterpret_cast<const f16x4*>(&T[row][q * 16 + 4]);
    f16x4 p2 = *reinterpret_cast<const f16x4*>(&T[row][q * 16 + 8]);
    f16x4 p3 = *reinterpret_cast<const f16x4*>(&T[row][q * 16 + 12]);
    f16* dst = exp16 + bb + (long)(m0g + row) * ES_ + es0 + q * 16;
    *reinterpret_cast<f16x8*>(dst)     = cat8(p0, p1);
    *reinterpret_cast<f16x8*>(dst + 8) = cat8(p2, p3);
  }
  // ---- phase 2b: write expT16 [es][m] rows (transpose from LDS) ----
  {
    const int er = t >> 2, q = t & 3;
    f16x4 g[4];
#pragma unroll
    for (int j = 0; j < 4; ++j)
#pragma unroll
      for (int i = 0; i < 4; ++i)
        g[j][i] = T[q * 16 + j * 4 + i][er];
    f16* dst = expT16 + bb + (long)(es0 + er) * M_ + m0g + q * 16;
    *reinterpret_cast<f16x8*>(dst)     = cat8(g[0], g[1]);
    *reinterpret_cast<f16x8*>(dst + 8) = cat8(g[2], g[3]);
  }
  // ---- phase 2c: partial sums ----
  if (t < 64) {            // row sums (per m, over this es-slice)
    float s = 0.f;
#pragma unroll
    for (int i = 0; i < 16; ++i) {
      const f16x4 v = *reinterpret_cast<const f16x4*>(&T[t][i * 4]);
      s += (float)v[0] + (float)v[1] + (float)v[2] + (float)v[3];
    }
    rowpart[((long)bz * 256 + m0g + t) * 4 + blockIdx.x] = s;
  } else if (t < 128) {    // col sums (per es, over this m-slice)
    const int es = t - 64;
    float s = 0.f;
#pragma unroll
    for (int i = 0; i < 64; ++i) s += (float)T[i][es];
    colpart[((long)bz * 256 + es0 + es) * 4 + blockIdx.y] = s;
  }
}

// ===========================================================================
// k_slots_s: slots16[b][es][d] = softmax-normalized dispatch^T @ obs
//   = (1/colsum[es]) * expT16[b] @ obsT16[b]^T        (K = m)
// grid (4 d, 4 es, 64 b), 256 threads
// ===========================================================================
__global__ __launch_bounds__(256) void k_slots_s(
    const f16* __restrict__ expT16, const f16* __restrict__ obsT16,
    const float* __restrict__ colpart, f16* __restrict__ slots16)
{
  const int t = threadIdx.x;
  const int w = t >> 6, lane = t & 63;
  const int wr = w >> 1, wc = w & 1;
  const int m0 = blockIdx.y * 64 + wr * 32;   // es rows
  const int n0 = blockIdx.x * 64 + wc * 32;   // d cols
  const int lr = lane & 15, lk = (lane >> 4) * 8;
  const long b = blockIdx.z;

  f32x4 acc[2][2] = {};
  const f16* Ap = expT16 + b * (ES_ * M_) + (long)(m0 + lr) * M_ + lk;
  const f16* Bp = obsT16 + b * (D_ * M_) + (long)(n0 + lr) * M_ + lk;
#pragma unroll
  for (int k0 = 0; k0 < M_; k0 += 32) {
    const f16x8 a0 = *reinterpret_cast<const f16x8*>(Ap + k0);
    const f16x8 a1 = *reinterpret_cast<const f16x8*>(Ap + 16 * M_ + k0);
    const f16x8 b0 = *reinterpret_cast<const f16x8*>(Bp + k0);
    const f16x8 b1 = *reinterpret_cast<const f16x8*>(Bp + 16 * M_ + k0);
    acc[0][0] = __builtin_amdgcn_mfma_f32_16x16x32_f16(a0, b0, acc[0][0], 0, 0, 0);
    acc[0][1] = __builtin_amdgcn_mfma_f32_16x16x32_f16(a0, b1, acc[0][1], 0, 0, 0);
    acc[1][0] = __builtin_amdgcn_mfma_f32_16x16x32_f16(a1, b0, acc[1][0], 0, 0, 0);
    acc[1][1] = __builtin_amdgcn_mfma_f32_16x16x32_f16(a1, b1, acc[1][1], 0, 0, 0);
  }

  const int orow = (lane >> 4) * 4;
  f16* C = slots16 + b * (ES_ * D_);
#pragma unroll
  for (int fi = 0; fi < 2; ++fi) {
    float inv[4];
#pragma unroll
    for (int r = 0; r < 4; ++r) {
      const int gm = m0 + fi * 16 + orow + r;
      const float4 cp = *reinterpret_cast<const float4*>(&colpart[((long)b * 256 + gm) * 4]);
      inv[r] = 1.0f / (cp.x + cp.y + cp.z + cp.w);
    }
#pragma unroll
    for (int fj = 0; fj < 2; ++fj) {
      const int gm = m0 + fi * 16 + orow;
      const int gn = n0 + fj * 16 + lr;
#pragma unroll
      for (int r = 0; r < 4; ++r)
        C[(long)(gm + r) * D_ + gn] = (f16)(acc[fi][fj][r] * inv[r]);
    }
  }
}

// ===========================================================================
// k_out_s: out[b][m][d] (fp32) = (1/rowsum[m]) * exp16[b] @ yT16[b]^T  (K=es)
// grid (4 d, 4 m, 64 b), 256 threads
// ===========================================================================
__global__ __launch_bounds__(256) void k_out_s(
    const f16* __restrict__ exp16, const f16* __restrict__ yT16,
    const float* __restrict__ rowpart, float* __restrict__ out)
{
  const int t = threadIdx.x;
  const int w = t >> 6, lane = t & 63;
  const int wr = w >> 1, wc = w & 1;
  const int m0 = blockIdx.y * 64 + wr * 32;   // m rows
  const int n0 = blockIdx.x * 64 + wc * 32;   // d cols
  const int lr = lane & 15, lk = (lane >> 4) * 8;
  const long b = blockIdx.z;

  f32x4 acc[2][2] = {};
  const f16* Ap = exp16 + b * (M_ * ES_) + (long)(m0 + lr) * ES_ + lk;
  const f16* Bp = yT16 + b * (D_ * ES_) + (long)(n0 + lr) * ES_ + lk;
#pragma unroll
  for (int k0 = 0; k0 < ES_; k0 += 32) {
    const f16x8 a0 = *reinterpret_cast<const f16x8*>(Ap + k0);
    const f16x8 a1 = *reinterpret_cast<const f16x8*>(Ap + 16 * ES_ + k0);
    const f16x8 b0 = *reinterpret_cast<const f16x8*>(Bp + k0);
    const f16x8 b1 = *reinterpret_cast<const f16x8*>(Bp + 16 * ES_ + k0);
    acc[0][0] = __builtin_amdgcn_mfma_f32_16x16x32_f16(a0, b0, acc[0][0], 0, 0, 0);
    acc[0][1] = __builtin_amdgcn_mfma_f32_16x16x32_f16(a0, b1, acc[0][1], 0, 0, 0);
    acc[1][0] = __builtin_amdgcn_mfma_f32_16x16x32_f16(a1, b0, acc[1][0], 0, 0, 0);
    acc[1][1] = __builtin_amdgcn_mfma_f32_16x16x32_f16(a1, b1, acc[1][1], 0, 0, 0);
  }

  const int orow = (lane >> 4) * 4;
  float* C = out + b * (M_ * D_);
#pragma unroll
  for (int fi = 0; fi < 2; ++fi) {
    float inv[4];
#pragma unroll
    for (int r = 0; r < 4; ++r) {
      const int gm = m0 + fi * 16 + orow + r;
      const float4 rp = *reinterpret_cast<const float4*>(&rowpart[((long)b * 256 + gm) * 4]);
      inv[r] = 1.0f / (rp.x + rp.y + rp.z + rp.w);
    }
#pragma unroll
    for (int fj = 0; fj < 2; ++fj) {
      const int gm = m0 + fi * 16 + orow;
      const int gn = n0 + fj * 16 + lr;
#pragma unroll
      for (int r = 0; r < 4; ++r)
        C[(long)(gm + r) * D_ + gn] = acc[fi][fj][r] * inv[r];
    }
  }
}

// ===========================================================================
// k_hy2: fused h->y per (b,e,s-slice of 32): h = relu(slots @ w1T^T + b1)
// in LDS (32x520 f16, 33 KB), then yT16 = (h @ w2T[a-slice]^T + b2)^T.
// 512 threads = 8 waves; 512 blocks; 2 blocks/CU target.
// ===========================================================================
#define HPAD2 520

__global__ __launch_bounds__(512, 4) void k_hy2(
    const f16* __restrict__ slots16, const f16* __restrict__ w1T,
    const float* __restrict__ b1, const f16* __restrict__ w2T,
    const float* __restrict__ b2, const int* __restrict__ action,
    f16* __restrict__ yT16)
{
  __shared__ f16 hs[32][HPAD2];
  const int bx = blockIdx.x;
  const int z = bx >> 1, half = bx & 1;
  const int b = z >> 2, e = z & 3;
  const int s0 = half * 32;
  int a = action[b];
  a = (a < 0) ? 0 : (a >= A_ ? A_ - 1 : a);

  const int t = threadIdx.x, w = t >> 6, lane = t & 63;
  const int lr = lane & 15, lk = (lane >> 4) * 8;
  const int orow = (lane >> 4) * 4;

  // GEMM2 B pointer: wave w covers y-cols w*32 .. w*32+31
  const f16* Bp2 = w2T + (long)e * ((long)K2_ * H_)
                 + ((long)a * D_ + w * 32 + lr) * H_ + lk;

  // ---- GEMM1: h[32][512] = relu(slots[s-slice 32 x 256] @ w1T^T + b1) -----
  {
    const int n0 = w * 64;
    f32x4 acc[2][4] = {};
    const f16* Ap = slots16 + (long)z * (S_ * D_) + (long)(s0 + lr) * D_ + lk;
    const f16* Bp = w1T + (long)e * (H_ * D_) + (long)(n0 + lr) * D_ + lk;

    f16x8 afc[2], bfc[4], afn[2], bfn[4];
#pragma unroll
    for (int fi = 0; fi < 2; ++fi)
      afc[fi] = *reinterpret_cast<const f16x8*>(Ap + (long)fi * 16 * D_);
#pragma unroll
    for (int fj = 0; fj < 4; ++fj)
      bfc[fj] = *reinterpret_cast<const f16x8*>(Bp + (long)fj * 16 * D_);

#pragma unroll
    for (int it = 0; it < 8; ++it) {
      const int k1 = (it + 1) * 32;
      if (it < 7) {
#pragma unroll
        for (int fi = 0; fi < 2; ++fi)
          afn[fi] = *reinterpret_cast<const f16x8*>(Ap + (long)fi * 16 * D_ + k1);
#pragma unroll
        for (int fj = 0; fj < 4; ++fj)
          bfn[fj] = *reinterpret_cast<const f16x8*>(Bp + (long)fj * 16 * D_ + k1);
      }
#pragma unroll
      for (int fi = 0; fi < 2; ++fi)
#pragma unroll
        for (int fj = 0; fj < 4; ++fj)
          acc[fi][fj] = __builtin_amdgcn_mfma_f32_16x16x32_f16(
              afc[fi], bfc[fj], acc[fi][fj], 0, 0, 0);
#pragma unroll
      for (int q = 0; q < 2; ++q) afc[q] = afn[q];
#pragma unroll
      for (int q = 0; q < 4; ++q) bfc[q] = bfn[q];
    }
#pragma unroll
    for (int fi = 0; fi < 2; ++fi)
#pragma unroll
      for (int fj = 0; fj < 4; ++fj) {
        const int gm = fi * 16 + orow;
        const int gn = n0 + fj * 16 + lr;
        const float bv = b1[e * H_ + gn];
#pragma unroll
        for (int r = 0; r < 4; ++r)
          hs[gm + r][gn] = (f16)fmaxf(acc[fi][fj][r] + bv, 0.f);
      }
  }

  // Prefetch GEMM2's first B fragments (independent of LDS) under the barrier
  f16x8 bfc2[2], bfn2[2];
#pragma unroll
  for (int fj = 0; fj < 2; ++fj)
    bfc2[fj] = *reinterpret_cast<const f16x8*>(Bp2 + (long)fj * 16 * H_);

  __syncthreads();

  // ---- GEMM2: y[32 s][32 d per wave] = h @ w2T[a-slice]^T + b2 ------------
  {
    const int n0 = w * 32;
    f32x4 acc[2][2] = {};
#pragma unroll
    for (int it = 0; it < 16; ++it) {
      const int k0 = it * 32;
      f16x8 af[2];
#pragma unroll
      for (int fi = 0; fi < 2; ++fi)
        af[fi] = *reinterpret_cast<const f16x8*>(&hs[fi * 16 + lr][k0 + lk]);
      if (it < 15) {
#pragma unroll
        for (int fj = 0; fj < 2; ++fj)
          bfn2[fj] = *reinterpret_cast<const f16x8*>(
              Bp2 + (long)fj * 16 * H_ + k0 + 32);
      }
#pragma unroll
      for (int fi = 0; fi < 2; ++fi)
#pragma unroll
        for (int fj = 0; fj < 2; ++fj)
          acc[fi][fj] = __builtin_amdgcn_mfma_f32_16x16x32_f16(
              af[fi], bfc2[fj], acc[fi][fj], 0, 0, 0);
#pragma unroll
      for (int q = 0; q < 2; ++q) bfc2[q] = bfn2[q];
    }
    // transposed write: yT16[b][d][es = e*64 + s0 + s]
#pragma unroll
    for (int fi = 0; fi < 2; ++fi)
#pragma unroll
      for (int fj = 0; fj < 2; ++fj) {
        const int gm = fi * 16 + orow;           // s within slice
        const int gn = n0 + fj * 16 + lr;        // d
        const float bv = b2[e * K2_ + a * D_ + gn];
        f16x4 h4;
#pragma unroll
        for (int r = 0; r < 4; ++r) h4[r] = (f16)(acc[fi][fj][r] + bv);
        *reinterpret_cast<f16x4*>(
            &yT16[(long)b * (D_ * ES_) + (long)gn * ES_ + e * S_ + s0 + gm]) = h4;
      }
  }
}

// ===========================================================================
extern "C" void kernel_launch(void* const* d_in, const int* in_sizes, int n_in,
                              void* d_out, int out_size, void* d_ws, size_t ws_size,
                              hipStream_t stream)
{
  const float* obs    = (const float*)d_in[0];
  const int*   action = (const int*)d_in[1];
  const float* phi    = (const float*)d_in[2];
  const float* w1     = (const float*)d_in[3];
  const float* b1     = (const float*)d_in[4];
  const float* w2     = (const float*)d_in[5];
  const float* b2     = (const float*)d_in[6];
  float*       out    = (float*)d_out;

  // Workspace layout (f16 units), ~71 MB total
  f16* ws = (f16*)d_ws;
  f16* obs16    = ws + 0;          // 4,194,304
  f16* obsT16   = ws + 4194304;    // 4,194,304
  f16* phiT     = ws + 8388608;    //    65,536
  f16* w1T      = ws + 8454144;    //   524,288
  f16* w2T      = ws + 8978432;    // 9,437,184
  f16* exp16    = ws + 18415616;   // 4,194,304
  f16* expT16   = ws + 22609920;   // 4,194,304
  f16* slots16  = ws + 26804224;   // 4,194,304
  f16* yT16     = ws + 30998528;   // 4,194,304
  float* rowpart = (float*)(ws + 35192832);  // 65,536 f32
  float* colpart = (float*)(ws + 35323904);  // 65,536 f32

  // --- one-time conversions ---
  k_cvt_obs<<<dim3(4, 4, 64), 256, 0, stream>>>(obs, obs16, obsT16);
  k_tcvt   <<<dim3(4, 4, 1),  256, 0, stream>>>(phi, phiT, 256, 256, 0, 0);
  k_tcvt   <<<dim3(8, 4, 4),  256, 0, stream>>>(w1, w1T, D_, H_,
                                                (long)D_ * H_, (long)H_ * D_);
  k_tcvt   <<<dim3(72, 8, 4), 256, 0, stream>>>(w2, w2T, H_, K2_,
                                                (long)H_ * K2_, (long)K2_ * H_);
  // --- pipeline ---
  k_logits_f<<<dim3(4, 4, 64), 256, 0, stream>>>(obs16, phiT, exp16, expT16,
                                                 rowpart, colpart);
  k_slots_s <<<dim3(4, 4, 64), 256, 0, stream>>>(expT16, obsT16, colpart, slots16);
  k_hy2     <<<dim3(512),      512, 0, stream>>>(slots16, w1T, b1, w2T, b2,
                                                 action, yT16);
  k_out_s   <<<dim3(4, 4, 64), 256, 0, stream>>>(exp16, yT16, rowpart, out);
}

// Round 9
// 119.030 us; speedup vs baseline: 1.4253x; 1.0207x over previous
//
#include <hip/hip_runtime.h>

// Problem constants
#define B_   64
#define M_   256
#define D_   256
#define A_   18
#define E_   4
#define S_   64
#define ES_  256          // E_*S_ == M_
#define H_   512
#define K2_  (A_*D_)      // 4608

typedef _Float16 f16;
typedef _Float16 f16x4 __attribute__((ext_vector_type(4)));
typedef _Float16 f16x8 __attribute__((ext_vector_type(8)));
typedef float    f32x4 __attribute__((ext_vector_type(4)));
typedef float    f32x8 __attribute__((ext_vector_type(8)));

static __device__ __forceinline__ f16x8 cat8(f16x4 a, f16x4 b) {
  return __builtin_shufflevector(a, b, 0, 1, 2, 3, 4, 5, 6, 7);
}
static __device__ __forceinline__ f16x8 pack8(float4 u0, float4 u1) {
  f16x8 a;
  a[0] = (f16)u0.x; a[1] = (f16)u0.y; a[2] = (f16)u0.z; a[3] = (f16)u0.w;
  a[4] = (f16)u1.x; a[5] = (f16)u1.y; a[6] = (f16)u1.z; a[7] = (f16)u1.w;
  return a;
}
static __device__ __forceinline__ f16x8 cvt8(f32x8 v) {
  f16x8 h;
#pragma unroll
  for (int j = 0; j < 8; ++j) h[j] = (f16)v[j];
  return h;
}
// 8 strided dword loads from w2 fp32: element (k0+lk+j, col) with row stride K2_
static __device__ __forceinline__ f32x8 loadw8(const float* __restrict__ p,
                                               int k0, int lk) {
  f32x8 v;
#pragma unroll
  for (int j = 0; j < 8; ++j) v[j] = p[(long)(k0 + lk + j) * K2_];
  return v;
}

// ===========================================================================
// k_sched: order[rank(b)] = b, ranked by (action[b], b). 1 block, 64 threads.
// ===========================================================================
__global__ __launch_bounds__(64) void k_sched(
    const int* __restrict__ action, int* __restrict__ order)
{
  const int t = threadIdx.x;
  const int a = action[t];
  int rank = 0;
#pragma unroll 8
  for (int i = 0; i < B_; ++i) {
    const int ai = action[i];
    rank += (ai < a) || (ai == a && i < t);
  }
  order[rank] = t;
}

// ===========================================================================
// fp32 src [z][R][C] -> fp16 dst [z][C][R]  (transpose + convert) — w1, phi
// ===========================================================================
__global__ __launch_bounds__(256) void k_tcvt(
    const float* __restrict__ src, f16* __restrict__ dst,
    int R, int C, long sbs, long dbs)
{
  __shared__ f16 T[64][68];
  const int t = threadIdx.x;
  const int rr = t >> 4, cc = (t & 15) * 4;
  const int r0 = blockIdx.y * 64, c0 = blockIdx.x * 64;
  src += (long)blockIdx.z * sbs;
  dst += (long)blockIdx.z * dbs;
#pragma unroll
  for (int p = 0; p < 4; ++p) {
    const int row = rr + p * 16;
    const float4 v = *reinterpret_cast<const float4*>(
        &src[(long)(r0 + row) * C + c0 + cc]);
    T[row][cc + 0] = (f16)v.x; T[row][cc + 1] = (f16)v.y;
    T[row][cc + 2] = (f16)v.z; T[row][cc + 3] = (f16)v.w;
  }
  __syncthreads();
#pragma unroll
  for (int p = 0; p < 4; ++p) {
    const int oc = rr + p * 16;
    f16x4 g;
#pragma unroll
    for (int i = 0; i < 4; ++i) g[i] = T[cc + i][oc];
    *reinterpret_cast<f16x4*>(&dst[(long)(c0 + oc) * R + r0 + cc]) = g;
  }
}

// obs fp32 [b][M][D] -> obsT16 [b][D][M]
__global__ __launch_bounds__(256) void k_cvt_obsT(
    const float* __restrict__ obs, f16* __restrict__ oT)
{
  __shared__ f16 T[64][68];
  const int t = threadIdx.x, rr = t >> 4, cc = (t & 15) * 4;
  const int r0 = blockIdx.y * 64, c0 = blockIdx.x * 64;
  const long bo = (long)blockIdx.z * (M_ * D_);
#pragma unroll
  for (int p = 0; p < 4; ++p) {
    const int row = rr + p * 16;
    const float4 v = *reinterpret_cast<const float4*>(
        &obs[bo + (long)(r0 + row) * D_ + c0 + cc]);
    T[row][cc + 0] = (f16)v.x; T[row][cc + 1] = (f16)v.y;
    T[row][cc + 2] = (f16)v.z; T[row][cc + 3] = (f16)v.w;
  }
  __syncthreads();
#pragma unroll
  for (int p = 0; p < 4; ++p) {
    const int oc = rr + p * 16;
    f16x4 g;
#pragma unroll
    for (int i = 0; i < 4; ++i) g[i] = T[cc + i][oc];
    *reinterpret_cast<f16x4*>(&oT[bo + (long)(c0 + oc) * M_ + r0 + cc]) = g;
  }
}

// ===========================================================================
// k_logits_f: per 64x64 tile of logits[b] = obs_fp32[b] @ phiT^T:
//   exp16 [b][m][es], expT16[b][es][m], rowpart/colpart partial sums.
// A-fragments read fp32 obs directly (contiguous), converted in-register.
// grid (4 es, 4 m, 64 b), 256 threads
// ===========================================================================
__global__ __launch_bounds__(256) void k_logits_f(
    const float* __restrict__ obs, const f16* __restrict__ phiT,
    f16* __restrict__ exp16, f16* __restrict__ expT16,
    float* __restrict__ rowpart, float* __restrict__ colpart)
{
  __shared__ f16 T[64][68];
  const int t = threadIdx.x;
  const int es0 = blockIdx.x * 64, m0g = blockIdx.y * 64;
  const int bz = blockIdx.z;
  const long bo = (long)bz * (M_ * D_);
  const long bb = (long)bz * (M_ * ES_);

  const int w = t >> 6, lane = t & 63;
  const int wr = w >> 1, wc = w & 1;
  const int lr = lane & 15, lk = (lane >> 4) * 8;
  const int orow = (lane >> 4) * 4;

  f32x4 acc[2][2] = {};
  const float* Ap = obs + bo + (long)(m0g + wr * 32 + lr) * D_ + lk;
  const f16*   Bp = phiT + (long)(es0 + wc * 32 + lr) * D_ + lk;
#pragma unroll
  for (int k0 = 0; k0 < D_; k0 += 32) {
    const float4 u00 = *reinterpret_cast<const float4*>(Ap + k0);
    const float4 u01 = *reinterpret_cast<const float4*>(Ap + k0 + 4);
    const float4 u10 = *reinterpret_cast<const float4*>(Ap + 16 * D_ + k0);
    const float4 u11 = *reinterpret_cast<const float4*>(Ap + 16 * D_ + k0 + 4);
    const f16x8 a0 = pack8(u00, u01);
    const f16x8 a1 = pack8(u10, u11);
    const f16x8 b0 = *reinterpret_cast<const f16x8*>(Bp + k0);
    const f16x8 b1 = *reinterpret_cast<const f16x8*>(Bp + 16 * D_ + k0);
    acc[0][0] = __builtin_amdgcn_mfma_f32_16x16x32_f16(a0, b0, acc[0][0], 0, 0, 0);
    acc[0][1] = __builtin_amdgcn_mfma_f32_16x16x32_f16(a0, b1, acc[0][1], 0, 0, 0);
    acc[1][0] = __builtin_amdgcn_mfma_f32_16x16x32_f16(a1, b0, acc[1][0], 0, 0, 0);
    acc[1][1] = __builtin_amdgcn_mfma_f32_16x16x32_f16(a1, b1, acc[1][1], 0, 0, 0);
  }
#pragma unroll
  for (int fi = 0; fi < 2; ++fi)
#pragma unroll
    for (int fj = 0; fj < 2; ++fj) {
      const int gm = wr * 32 + fi * 16 + orow;
      const int gn = wc * 32 + fj * 16 + lr;
#pragma unroll
      for (int r = 0; r < 4; ++r)
        T[gm + r][gn] = (f16)__expf(acc[fi][fj][r]);
    }
  __syncthreads();

  {  // exp16 [m][es]
    const int row = t >> 2, q = t & 3;
    f16x4 p0 = *reinterpret_cast<const f16x4*>(&T[row][q * 16 + 0]);
    f16x4 p1 = *reinterpret_cast<const f16x4*>(&T[row][q * 16 + 4]);
    f16x4 p2 = *reinterpret_cast<const f16x4*>(&T[row][q * 16 + 8]);
    f16x4 p3 = *reinterpret_cast<const f16x4*>(&T[row][q * 16 + 12]);
    f16* dst = exp16 + bb + (long)(m0g + row) * ES_ + es0 + q * 16;
    *reinterpret_cast<f16x8*>(dst)     = cat8(p0, p1);
    *reinterpret_cast<f16x8*>(dst + 8) = cat8(p2, p3);
  }
  {  // expT16 [es][m]
    const int er = t >> 2, q = t & 3;
    f16x4 g[4];
#pragma unroll
    for (int j = 0; j < 4; ++j)
#pragma unroll
      for (int i = 0; i < 4; ++i)
        g[j][i] = T[q * 16 + j * 4 + i][er];
    f16* dst = expT16 + bb + (long)(es0 + er) * M_ + m0g + q * 16;
    *reinterpret_cast<f16x8*>(dst)     = cat8(g[0], g[1]);
    *reinterpret_cast<f16x8*>(dst + 8) = cat8(g[2], g[3]);
  }
  if (t < 64) {
    float s = 0.f;
#pragma unroll
    for (int i = 0; i < 16; ++i) {
      const f16x4 v = *reinterpret_cast<const f16x4*>(&T[t][i * 4]);
      s += (float)v[0] + (float)v[1] + (float)v[2] + (float)v[3];
    }
    rowpart[((long)bz * 256 + m0g + t) * 4 + blockIdx.x] = s;
  } else if (t < 128) {
    const int es = t - 64;
    float s = 0.f;
#pragma unroll
    for (int i = 0; i < 64; ++i) s += (float)T[i][es];
    colpart[((long)bz * 256 + es0 + es) * 4 + blockIdx.y] = s;
  }
}

// ===========================================================================
// k_slots_s: slots16[b][es][d] = (1/colsum[es]) * expT16[b] @ obsT16[b]^T
// grid (4 d, 4 es, 64 b), 256 threads
// ===========================================================================
__global__ __launch_bounds__(256) void k_slots_s(
    const f16* __restrict__ expT16, const f16* __restrict__ obsT16,
    const float* __restrict__ colpart, f16* __restrict__ slots16)
{
  const int t = threadIdx.x;
  const int w = t >> 6, lane = t & 63;
  const int wr = w >> 1, wc = w & 1;
  const int m0 = blockIdx.y * 64 + wr * 32;
  const int n0 = blockIdx.x * 64 + wc * 32;
  const int lr = lane & 15, lk = (lane >> 4) * 8;
  const long b = blockIdx.z;

  f32x4 acc[2][2] = {};
  const f16* Ap = expT16 + b * (ES_ * M_) + (long)(m0 + lr) * M_ + lk;
  const f16* Bp = obsT16 + b * (D_ * M_) + (long)(n0 + lr) * M_ + lk;
#pragma unroll
  for (int k0 = 0; k0 < M_; k0 += 32) {
    const f16x8 a0 = *reinterpret_cast<const f16x8*>(Ap + k0);
    const f16x8 a1 = *reinterpret_cast<const f16x8*>(Ap + 16 * M_ + k0);
    const f16x8 b0 = *reinterpret_cast<const f16x8*>(Bp + k0);
    const f16x8 b1 = *reinterpret_cast<const f16x8*>(Bp + 16 * M_ + k0);
    acc[0][0] = __builtin_amdgcn_mfma_f32_16x16x32_f16(a0, b0, acc[0][0], 0, 0, 0);
    acc[0][1] = __builtin_amdgcn_mfma_f32_16x16x32_f16(a0, b1, acc[0][1], 0, 0, 0);
    acc[1][0] = __builtin_amdgcn_mfma_f32_16x16x32_f16(a1, b0, acc[1][0], 0, 0, 0);
    acc[1][1] = __builtin_amdgcn_mfma_f32_16x16x32_f16(a1, b1, acc[1][1], 0, 0, 0);
  }

  const int orow = (lane >> 4) * 4;
  f16* C = slots16 + b * (ES_ * D_);
#pragma unroll
  for (int fi = 0; fi < 2; ++fi) {
    float inv[4];
#pragma unroll
    for (int r = 0; r < 4; ++r) {
      const int gm = m0 + fi * 16 + orow + r;
      const float4 cp = *reinterpret_cast<const float4*>(&colpart[((long)b * 256 + gm) * 4]);
      inv[r] = 1.0f / (cp.x + cp.y + cp.z + cp.w);
    }
#pragma unroll
    for (int fj = 0; fj < 2; ++fj) {
      const int gm = m0 + fi * 16 + orow;
      const int gn = n0 + fj * 16 + lr;
#pragma unroll
      for (int r = 0; r < 4; ++r)
        C[(long)(gm + r) * D_ + gn] = (f16)(acc[fi][fj][r] * inv[r]);
    }
  }
}

// ===========================================================================
// k_out_s: out[b][m][d] (fp32) = (1/rowsum[m]) * exp16[b] @ yT16[b]^T
// grid (4 d, 4 m, 64 b), 256 threads
// ===========================================================================
__global__ __launch_bounds__(256) void k_out_s(
    const f16* __restrict__ exp16, const f16* __restrict__ yT16,
    const float* __restrict__ rowpart, float* __restrict__ out)
{
  const int t = threadIdx.x;
  const int w = t >> 6, lane = t & 63;
  const int wr = w >> 1, wc = w & 1;
  const int m0 = blockIdx.y * 64 + wr * 32;
  const int n0 = blockIdx.x * 64 + wc * 32;
  const int lr = lane & 15, lk = (lane >> 4) * 8;
  const long b = blockIdx.z;

  f32x4 acc[2][2] = {};
  const f16* Ap = exp16 + b * (M_ * ES_) + (long)(m0 + lr) * ES_ + lk;
  const f16* Bp = yT16 + b * (D_ * ES_) + (long)(n0 + lr) * ES_ + lk;
#pragma unroll
  for (int k0 = 0; k0 < ES_; k0 += 32) {
    const f16x8 a0 = *reinterpret_cast<const f16x8*>(Ap + k0);
    const f16x8 a1 = *reinterpret_cast<const f16x8*>(Ap + 16 * ES_ + k0);
    const f16x8 b0 = *reinterpret_cast<const f16x8*>(Bp + k0);
    const f16x8 b1 = *reinterpret_cast<const f16x8*>(Bp + 16 * ES_ + k0);
    acc[0][0] = __builtin_amdgcn_mfma_f32_16x16x32_f16(a0, b0, acc[0][0], 0, 0, 0);
    acc[0][1] = __builtin_amdgcn_mfma_f32_16x16x32_f16(a0, b1, acc[0][1], 0, 0, 0);
    acc[1][0] = __builtin_amdgcn_mfma_f32_16x16x32_f16(a1, b0, acc[1][0], 0, 0, 0);
    acc[1][1] = __builtin_amdgcn_mfma_f32_16x16x32_f16(a1, b1, acc[1][1], 0, 0, 0);
  }

  const int orow = (lane >> 4) * 4;
  float* C = out + b * (M_ * D_);
#pragma unroll
  for (int fi = 0; fi < 2; ++fi) {
    float inv[4];
#pragma unroll
    for (int r = 0; r < 4; ++r) {
      const int gm = m0 + fi * 16 + orow + r;
      const float4 rp = *reinterpret_cast<const float4*>(&rowpart[((long)b * 256 + gm) * 4]);
      inv[r] = 1.0f / (rp.x + rp.y + rp.z + rp.w);
    }
#pragma unroll
    for (int fj = 0; fj < 2; ++fj) {
      const int gm = m0 + fi * 16 + orow;
      const int gn = n0 + fj * 16 + lr;
#pragma unroll
      for (int r = 0; r < 4; ++r)
        C[(long)(gm + r) * D_ + gn] = acc[fi][fj][r] * inv[r];
    }
  }
}

// ===========================================================================
// k_hy3: fused h->y per (b,e,half-of-s). 512 blocks, 512 threads.
// Block decode: XCD-chunk swizzle (8 chunks of 64) -> {e major, action-sorted
// b, half minor}: blocks sharing the (e, action) w2 slice run adjacently on
// the SAME XCD -> w2 slice is fetched from HBM once, then L2-hit.
// GEMM2 reads w2 fp32 DIRECTLY (strided dwords, in-register cvt), depth-2
// prefetch; first stage issued before GEMM1 to hide under it.
// ===========================================================================
#define HPAD2 520

__global__ __launch_bounds__(512, 4) void k_hy3(
    const f16* __restrict__ slots16, const f16* __restrict__ w1T,
    const float* __restrict__ b1, const float* __restrict__ w2,
    const float* __restrict__ b2, const int* __restrict__ action,
    const int* __restrict__ order, f16* __restrict__ yT16)
{
  __shared__ f16 hs[32][HPAD2];
  const int bx = blockIdx.x;
  const int L  = (bx & 7) * 64 + (bx >> 3);   // bijective, 512 % 8 == 0
  const int e = L >> 7, sb = (L >> 1) & 63, half = L & 1;
  const int b = order[sb];
  const int s0 = half * 32;
  int a = action[b];
  a = (a < 0) ? 0 : (a >= A_ ? A_ - 1 : a);
  const long z = (long)b * 4 + e;

  const int t = threadIdx.x, w = t >> 6, lane = t & 63;
  const int lr = lane & 15, lk = (lane >> 4) * 8;
  const int orow = (lane >> 4) * 4;

  // GEMM2 B base pointers (wave w covers y-cols w*32 .. w*32+31)
  const int n0_2 = w * 32;
  const float* Wp0 = w2 + (long)e * H_ * K2_ + (long)a * D_ + n0_2 + lr;
  const float* Wp1 = Wp0 + 16;

  // stage-A prefetch of w2 (k=0..31) issued before GEMM1
  f32x8 wA0 = loadw8(Wp0, 0, lk);
  f32x8 wA1 = loadw8(Wp1, 0, lk);

  // ---- GEMM1: h[32][512] = relu(slots[32x256] @ w1T[e]^T + b1) ------------
  {
    const int n0 = w * 64;
    f32x4 acc[2][4] = {};
    const f16* Ap = slots16 + z * (S_ * D_) + (long)(s0 + lr) * D_ + lk;
    const f16* Bp = w1T + (long)e * (H_ * D_) + (long)(n0 + lr) * D_ + lk;

    f16x8 afc[2], bfc[4], afn[2], bfn[4];
#pragma unroll
    for (int fi = 0; fi < 2; ++fi)
      afc[fi] = *reinterpret_cast<const f16x8*>(Ap + (long)fi * 16 * D_);
#pragma unroll
    for (int fj = 0; fj < 4; ++fj)
      bfc[fj] = *reinterpret_cast<const f16x8*>(Bp + (long)fj * 16 * D_);

#pragma unroll
    for (int it = 0; it < 8; ++it) {
      const int k1 = (it + 1) * 32;
      if (it < 7) {
#pragma unroll
        for (int fi = 0; fi < 2; ++fi)
          afn[fi] = *reinterpret_cast<const f16x8*>(Ap + (long)fi * 16 * D_ + k1);
#pragma unroll
        for (int fj = 0; fj < 4; ++fj)
          bfn[fj] = *reinterpret_cast<const f16x8*>(Bp + (long)fj * 16 * D_ + k1);
      }
#pragma unroll
      for (int fi = 0; fi < 2; ++fi)
#pragma unroll
        for (int fj = 0; fj < 4; ++fj)
          acc[fi][fj] = __builtin_amdgcn_mfma_f32_16x16x32_f16(
              afc[fi], bfc[fj], acc[fi][fj], 0, 0, 0);
#pragma unroll
      for (int q = 0; q < 2; ++q) afc[q] = afn[q];
#pragma unroll
      for (int q = 0; q < 4; ++q) bfc[q] = bfn[q];
    }
#pragma unroll
    for (int fi = 0; fi < 2; ++fi)
#pragma unroll
      for (int fj = 0; fj < 4; ++fj) {
        const int gm = fi * 16 + orow;
        const int gn = n0 + fj * 16 + lr;
        const float bv = b1[e * H_ + gn];
#pragma unroll
        for (int r = 0; r < 4; ++r)
          hs[gm + r][gn] = (f16)fmaxf(acc[fi][fj][r] + bv, 0.f);
      }
  }

  // stage-B prefetch (k=32..63) issued before the barrier
  f32x8 wB0 = loadw8(Wp0, 32, lk);
  f32x8 wB1 = loadw8(Wp1, 32, lk);

  __syncthreads();

  // ---- GEMM2: y[32 s][32 d per wave] = h @ w2[a-slice] + b2 ---------------
  {
    f32x4 acc[2][2] = {};
#pragma unroll
    for (int it = 0; it < 16; ++it) {
      const int k0 = it * 32;
      f16x8 b0, b1f;
      if ((it & 1) == 0) {
        b0 = cvt8(wA0); b1f = cvt8(wA1);
        if (it + 2 < 16) { wA0 = loadw8(Wp0, k0 + 64, lk);
                           wA1 = loadw8(Wp1, k0 + 64, lk); }
      } else {
        b0 = cvt8(wB0); b1f = cvt8(wB1);
        if (it + 2 < 16) { wB0 = loadw8(Wp0, k0 + 64, lk);
                           wB1 = loadw8(Wp1, k0 + 64, lk); }
      }
      f16x8 af[2];
#pragma unroll
      for (int fi = 0; fi < 2; ++fi)
        af[fi] = *reinterpret_cast<const f16x8*>(&hs[fi * 16 + lr][k0 + lk]);
      acc[0][0] = __builtin_amdgcn_mfma_f32_16x16x32_f16(af[0], b0,  acc[0][0], 0, 0, 0);
      acc[0][1] = __builtin_amdgcn_mfma_f32_16x16x32_f16(af[0], b1f, acc[0][1], 0, 0, 0);
      acc[1][0] = __builtin_amdgcn_mfma_f32_16x16x32_f16(af[1], b0,  acc[1][0], 0, 0, 0);
      acc[1][1] = __builtin_amdgcn_mfma_f32_16x16x32_f16(af[1], b1f, acc[1][1], 0, 0, 0);
    }
    // transposed write: yT16[b][d][es = e*64 + s0 + s]
#pragma unroll
    for (int fi = 0; fi < 2; ++fi)
#pragma unroll
      for (int fj = 0; fj < 2; ++fj) {
        const int gm = fi * 16 + orow;           // s within slice
        const int gn = n0_2 + fj * 16 + lr;      // d
        const float bv = b2[e * K2_ + a * D_ + gn];
        f16x4 h4;
#pragma unroll
        for (int r = 0; r < 4; ++r) h4[r] = (f16)(acc[fi][fj][r] + bv);
        *reinterpret_cast<f16x4*>(
            &yT16[(long)b * (D_ * ES_) + (long)gn * ES_ + e * S_ + s0 + gm]) = h4;
      }
  }
}

// ===========================================================================
extern "C" void kernel_launch(void* const* d_in, const int* in_sizes, int n_in,
                              void* d_out, int out_size, void* d_ws, size_t ws_size,
                              hipStream_t stream)
{
  const float* obs    = (const float*)d_in[0];
  const int*   action = (const int*)d_in[1];
  const float* phi    = (const float*)d_in[2];
  const float* w1     = (const float*)d_in[3];
  const float* b1     = (const float*)d_in[4];
  const float* w2     = (const float*)d_in[5];
  const float* b2     = (const float*)d_in[6];
  float*       out    = (float*)d_out;

  // Workspace (f16 units), ~44 MB total
  f16* ws = (f16*)d_ws;
  f16* obsT16  = ws + 0;          // 4,194,304
  f16* phiT    = ws + 4194304;    //    65,536
  f16* w1T     = ws + 4259840;    //   524,288
  f16* exp16   = ws + 4784128;    // 4,194,304
  f16* expT16  = ws + 8978432;    // 4,194,304
  f16* slots16 = ws + 13172736;   // 4,194,304
  f16* yT16    = ws + 17367040;   // 4,194,304
  float* rowpart = (float*)(ws + 21561344);   // 65,536 f32
  float* colpart = (float*)(ws + 21692416);   // 65,536 f32
  int*   order   = (int*)(ws + 21823488);     // 64 ints

  // --- prep ---
  k_sched   <<<dim3(1),        64,  0, stream>>>(action, order);
  k_cvt_obsT<<<dim3(4, 4, 64), 256, 0, stream>>>(obs, obsT16);
  k_tcvt    <<<dim3(4, 4, 1),  256, 0, stream>>>(phi, phiT, 256, 256, 0, 0);
  k_tcvt    <<<dim3(8, 4, 4),  256, 0, stream>>>(w1, w1T, D_, H_,
                                                 (long)D_ * H_, (long)H_ * D_);
  // --- pipeline ---
  k_logits_f<<<dim3(4, 4, 64), 256, 0, stream>>>(obs, phiT, exp16, expT16,
                                                 rowpart, colpart);
  k_slots_s <<<dim3(4, 4, 64), 256, 0, stream>>>(expT16, obsT16, colpart, slots16);
  k_hy3     <<<dim3(512),      512, 0, stream>>>(slots16, w1T, b1, w2, b2,
                                                 action, order, yT16);
  k_out_s   <<<dim3(4, 4, 64), 256, 0, stream>>>(exp16, yT16, rowpart, out);
}